// Round 5
// baseline (470.763 us; speedup 1.0000x reference)
//
#include <hip/hip_runtime.h>

typedef unsigned short u16;
typedef __attribute__((ext_vector_type(8))) short short8;   // 8 bf16 = 4 VGPRs (MFMA A/B frag)
typedef __attribute__((ext_vector_type(4))) float f32x4;    // MFMA C/D frag

#define T_SEQ 8192
#define DDIM 1024
#define BB 4
#define MM (BB * T_SEQ)      // 32768
#define NC 128               // chunks along T
#define CHUNK (T_SEQ / NC)   // 64
#define CHAINS (BB * DDIM)   // 4096
#define NHT 32               // half-tiles (K=32 each)

// ---------- helpers ----------
__device__ __forceinline__ float bf_lo(unsigned p) {
    union { unsigned u; float f; } v; v.u = p << 16; return v.f;
}
__device__ __forceinline__ float bf_hi(unsigned p) {
    union { unsigned u; float f; } v; v.u = p & 0xffff0000u; return v.f;
}
__device__ __forceinline__ float bf_u16(u16 p) {
    union { unsigned u; float f; } v; v.u = ((unsigned)p) << 16; return v.f;
}
__device__ __forceinline__ u16 f2bf(float f) {
    union { unsigned u; float f; } v; v.f = f;
    unsigned r = v.u + 0x7fffu + ((v.u >> 16) & 1u);   // RNE
    return (u16)(r >> 16);
}
__device__ __forceinline__ float sigm(float z) {
    return __builtin_amdgcn_rcpf(1.0f + __expf(-z));
}
__device__ __forceinline__ void gld16(const u16* g, u16* l) {
    __builtin_amdgcn_global_load_lds((const __attribute__((address_space(1))) void*)g,
                                     (__attribute__((address_space(3))) void*)l, 16, 0, 0);
}

// ---------- K1: fused fp32 -> bf16 convert for x, W_in, W_gate ----------
#define N4X (MM * DDIM / 4)      // 8388608 float4s
#define N4W (DDIM * DDIM / 4)    // 262144 float4s
__global__ __launch_bounds__(256) void cvt_all(const float* __restrict__ x,
                                               const float* __restrict__ Wi,
                                               const float* __restrict__ Wg,
                                               u16* __restrict__ Xb,
                                               u16* __restrict__ Wib,
                                               u16* __restrict__ Wgb) {
    int i = blockIdx.x * 256 + threadIdx.x;   // global float4 index
    const float* src; u16* dst; int j;
    if (i < N4X)            { src = x;  dst = Xb;  j = i; }
    else if (i < N4X + N4W) { src = Wi; dst = Wib; j = i - N4X; }
    else                    { src = Wg; dst = Wgb; j = i - N4X - N4W; }
    float4 v = ((const float4*)src)[j];
    ushort4 o;
    o.x = f2bf(v.x); o.y = f2bf(v.y); o.z = f2bf(v.z); o.w = f2bf(v.w);
    ((ushort4*)dst)[j] = o;
}

// ---------- K2: fused bf16 GEMM + gating epilogue (reg-pipelined schedule) ----------
// 8 waves (2M x 4N), virtual 256x256 tile (N: cols 0-127 Wi, 128-255 Wg).
// Per-wave 128x64 -> acc[8][4]. K = 32 half-tile pairs of K=32; LDS ring of 4
// slots. REGISTER PIPELINE (R4 post-mortem): frags for pair h+1 are ds_read
// DURING pair h's MFMAs into ping-pong sets (A0/A1 per phase, B0/B1 per pair
// parity), so at each barrier exit the MFMA operands are ALREADY in registers
// and the LDS service of the next pair's reads hides fully under the MFMA
// burst. R2/R3/R4 all issued reads in the consuming phase -> serial
// [LDS drain | MFMA] -> 33% MfmaUtil regardless of phase arrangement.
// Sync: ONE vmcnt + ONE barrier per pair (mid-pair): vmcnt(4) certifies slot
// h+1 (outstanding = slots h+1,h+2 = 8 rounds); barrier gates the slot-(h+1)
// reads and the staging overwrite of slot (h-1)&3 (whose reads completed
// before the reader's own MFMAs, hence before this barrier). Tail 4 -> 0.

#define MROW4(ri, af, bf)                                                               \
    acc[ri][0] = __builtin_amdgcn_mfma_f32_16x16x32_bf16(af, bf[0], acc[ri][0], 0,0,0); \
    acc[ri][1] = __builtin_amdgcn_mfma_f32_16x16x32_bf16(af, bf[1], acc[ri][1], 0,0,0); \
    acc[ri][2] = __builtin_amdgcn_mfma_f32_16x16x32_bf16(af, bf[2], acc[ri][2], 0,0,0); \
    acc[ri][3] = __builtin_amdgcn_mfma_f32_16x16x32_bf16(af, bf[3], acc[ri][3], 0,0,0);

#define MQUAD(b_, aset, bset) MROW4((b_)+0, aset[0], bset) MROW4((b_)+1, aset[1], bset) \
                              MROW4((b_)+2, aset[2], bset) MROW4((b_)+3, aset[3], bset)

// reads (swizzled) from compile-time ring slot s_
#define LDA_S(s_, i) (*(const short8*)&lds[(s_)*8192 + (arow0 + (i)*16)*32 + aoff])
#define LDB_S(s_, j) (*(const short8*)&lds[32768 + (s_)*8192 + (brow0 + (j)*16)*32 + aoff])

#define RD_A(dst, s_, base) { dst[0] = LDA_S(s_, (base)+0); dst[1] = LDA_S(s_, (base)+1); \
                              dst[2] = LDA_S(s_, (base)+2); dst[3] = LDA_S(s_, (base)+3); }
#define RD_B(dst, s_)       { dst[0] = LDB_S(s_, 0); dst[1] = LDB_S(s_, 1);               \
                              dst[2] = LDB_S(s_, 2); dst[3] = LDB_S(s_, 3); }

// staging rounds into compile-time slot ds_, from half-tile index ht_ (runtime OK)
#define STA_S(ds_, ht_, rb) gld16(gA + (size_t)(ht_)*32 + (size_t)(rb)*128*DDIM,       \
                                  &lds[(ds_)*8192 + (rb)*4096 + tid*8])
#define STB_S(ds_, ht_, hf) gld16(((hf) ? gBg : gBi) + (size_t)(ht_)*32,               \
                                  &lds[32768 + (ds_)*8192 + (hf)*4096 + tid*8])

// pair h: s_=h&3, sn_=(h+1)&3, ds_=(h+3)&3, BCUR=B(h&1), BNXT=B(1-(h&1))
#define PAIR_(s_, sn_, ds_, ht_, BCUR, BNXT, DOST, VMS, DORD)                          \
    /* PHASE_A: rows 0-3 of pair h; read own rows 4-7 (slot s_ certified) */           \
    RD_A(A1, s_, 4)                                                                    \
    __builtin_amdgcn_s_setprio(1);                                                     \
    MQUAD(0, A0, BCUR)                                                                 \
    __builtin_amdgcn_s_setprio(0);                                                     \
    asm volatile("s_waitcnt " VMS ::: "memory");  /* certify slot sn_ */               \
    __builtin_amdgcn_s_barrier();                                                      \
    /* PHASE_B: rows 4-7; prefetch pair h+1 frags; stage half-tile h+3 */              \
    if (DORD) { RD_B(BNXT, sn_) RD_A(A0, sn_, 0) }                                     \
    if (DOST) { STA_S(ds_, ht_, 0); STA_S(ds_, ht_, 1);                                \
                STB_S(ds_, ht_, 0); STB_S(ds_, ht_, 1); }                              \
    __builtin_amdgcn_s_setprio(1);                                                     \
    MQUAD(4, A1, BCUR)                                                                 \
    __builtin_amdgcn_s_setprio(0);

__global__ __launch_bounds__(512, 2)
void gemm_fused(const u16* __restrict__ X, const u16* __restrict__ Wi,
                const u16* __restrict__ Wg, const float* __restrict__ b_in,
                const float* __restrict__ b_gate, const float* __restrict__ lam,
                u16* __restrict__ Sg, u16* __restrict__ XBg) {
    const int bid = blockIdx.x;         // 0..1023
    const int xcd = bid & 7;
    const int r = bid >> 3;             // 0..127
    const int n_tile = r & 7;           // N fastest within an XCD
    const int m_tile = xcd * 16 + (r >> 3);
    const int tN0 = n_tile * 128;
    const int tM0 = m_tile * 256;

    const int tid = threadIdx.x;
    const int lane = tid & 63;
    const int w = tid >> 6;             // 0..7
    const int wm = w >> 2;              // 0..1 (M half)
    const int wn = w & 3;               // 0..3
    const int gate = wn >> 1;           // 0: IG, 1: RG
    const int wn_sub = wn & 1;

    __shared__ u16 lds[65536];          // 128KB: A ring [0,32768), B ring [32768,65536)

    // staging source pointers (per-thread, pre-swizzled column chunk)
    const int srow = tid >> 2;                          // 0..127
    const int c8log = (tid & 3) ^ ((tid >> 3) & 3);     // inverse swizzle on source
    const u16* gA  = X  + (size_t)(tM0 + srow) * DDIM + c8log * 8;
    const u16* gBi = Wi + (size_t)(tN0 + srow) * DDIM + c8log * 8;
    const u16* gBg = Wg + (size_t)(tN0 + srow) * DDIM + c8log * 8;

    // read-side constants
    const int lm = lane & 15;
    const int aoff = (((lane >> 4) ^ ((lm >> 1) & 3))) * 8;  // swizzled chunk, lane-only
    const int arow0 = wm * 128 + lm;                 // + i*16
    const int brow0 = gate * 128 + wn_sub * 64 + lm; // + j*16

    f32x4 acc[8][4] = {};
    short8 A0[4], A1[4], B0[4], B1[4];

    // ---- prologue: stage slots 0,1,2 (12 rounds); certify slot 0; preload pair 0 ----
    STA_S(0, 0, 0); STA_S(0, 0, 1); STB_S(0, 0, 0); STB_S(0, 0, 1);
    STA_S(1, 1, 0); STA_S(1, 1, 1); STB_S(1, 1, 0); STB_S(1, 1, 1);
    STA_S(2, 2, 0); STA_S(2, 2, 1); STB_S(2, 2, 0); STB_S(2, 2, 1);
    asm volatile("s_waitcnt vmcnt(8)" ::: "memory");   // slot 0 landed
    __builtin_amdgcn_s_barrier();
    RD_B(B0, 0) RD_A(A0, 0, 0)

    // ---- main loop: pairs 0..27 (ring-unrolled x4); pair h stages h+3 ----
    for (int g = 0; g < 7; ++g) {
        const int hb = 4 * g;
        PAIR_(0, 1, 3, hb + 3, B0, B1, 1, "vmcnt(4)", 1)
        PAIR_(1, 2, 0, hb + 4, B1, B0, 1, "vmcnt(4)", 1)
        PAIR_(2, 3, 1, hb + 5, B0, B1, 1, "vmcnt(4)", 1)
        PAIR_(3, 0, 2, hb + 6, B1, B0, 1, "vmcnt(4)", 1)
    }
    // ---- tail: pair 28 stages 31; 29/30 drain 4 -> 0; 31 computes only ----
    PAIR_(0, 1, 3, 31, B0, B1, 1, "vmcnt(4)", 1)
    PAIR_(1, 2, 0, 0,  B1, B0, 0, "vmcnt(4)", 1)
    PAIR_(2, 3, 0, 0,  B0, B1, 0, "vmcnt(0)", 1)
    PAIR_(3, 0, 0, 0,  B1, B0, 0, "vmcnt(0)", 0)
    asm volatile("s_waitcnt lgkmcnt(0)" ::: "memory");
    __builtin_amdgcn_s_barrier();        // all LDS reads done -> safe to reuse

    // ---- epilogue stage 1: dump per-acc values to LDS (XOR bank swizzle) ----
    // C/D layout: col=lane&15, row=(lane>>4)*4+rr. Local tile 256x128.
    // S region  lds[0,32768):      s  (bf16, == value the scan consumes)
    // P region  lds[32768,65536):  p  (u16 fixed-point /65535 -> err ~1e-5)
    const int r0 = (lane >> 4) << 2;
    const int cb = lane & 15;
    if (gate) {                          // RG waves: s = nsp*sigm(rg+b)
#pragma unroll
        for (int j = 0; j < 4; ++j) {
            const int colg = tN0 + wn_sub * 64 + j * 16 + cb;
            const int cl = wn_sub * 64 + j * 16 + cb;
            const float bj = b_gate[colg];
            const float nsp = -8.0f * log1pf(__expf(lam[colg]));
#pragma unroll
            for (int i = 0; i < 8; ++i) {
                const int rl0 = wm * 128 + i * 16 + r0;
#pragma unroll
                for (int rr = 0; rr < 4; ++rr) {
                    const int rl = rl0 + rr;
                    float s = nsp * sigm(acc[i][j][rr] + bj);
                    lds[rl * 128 + (cl ^ (((rl >> 2) & 7) << 4))] = f2bf(s);
                }
            }
        }
    } else {                             // IG waves: p = sigm(ig+b), fixed-point
#pragma unroll
        for (int j = 0; j < 4; ++j) {
            const int colg = tN0 + wn_sub * 64 + j * 16 + cb;
            const int cl = wn_sub * 64 + j * 16 + cb;
            const float bj = b_in[colg];
#pragma unroll
            for (int i = 0; i < 8; ++i) {
                const int rl0 = wm * 128 + i * 16 + r0;
#pragma unroll
                for (int rr = 0; rr < 4; ++rr) {
                    const int rl = rl0 + rr;
                    float p = sigm(acc[i][j][rr] + bj);
                    lds[32768 + rl * 128 + (cl ^ (((rl >> 2) & 7) << 4))] =
                        (u16)(p * 65535.0f + 0.5f);
                }
            }
        }
    }
    asm volatile("s_waitcnt lgkmcnt(0)" ::: "memory");
    __builtin_amdgcn_s_barrier();
    __builtin_amdgcn_sched_barrier(0);

    // ---- epilogue stage 2: vectorized combine + 16B stores ----
    // thread -> col-chunk cc (8 cols), rows rg0..rg0+7 (full 256x128 tile)
    const int cc = tid & 15;
    const int rg0 = (tid >> 4) * 8;
#pragma unroll
    for (int k = 0; k < 8; ++k) {
        const int rl = rg0 + k;
        const int ch = (cc ^ (((rl >> 2) & 7) << 1)) * 8;   // swizzled chunk base
        short8 sv = *(const short8*)&lds[rl * 128 + ch];
        short8 pv = *(const short8*)&lds[32768 + rl * 128 + ch];
        const size_t go = (size_t)(tM0 + rl) * DDIM + tN0 + cc * 8;
        short8 xv = *(const short8*)&X[go];
        short8 ov;
#pragma unroll
        for (int e = 0; e < 8; ++e) {
            float s = bf_u16((u16)sv[e]);
            float p = (float)((u16)pv[e]) * (1.0f / 65535.0f);
            float xf = bf_u16((u16)xv[e]);
            float be = sqrtf(1.0f - __expf(2.0f * s) + 1e-6f);
            ov[e] = (short)f2bf(be * p * xf);
        }
        *(short8*)&Sg[go] = sv;
        *(short8*)&XBg[go] = ov;
    }
}

// ---------- K3: pass1 — per-chunk aggregates (light: 1 exp + 2 fma / elem) ----------
__global__ __launch_bounds__(256)
void scan_pass1(const u16* __restrict__ S, const u16* __restrict__ XB,
                float* __restrict__ AggA, float* __restrict__ AggB) {
    const int c = blockIdx.x, dblk = blockIdx.y, bq = blockIdx.z;
    const int d0 = dblk * 512 + threadIdx.x * 2;
    size_t base = ((size_t)(bq * T_SEQ + c * CHUNK)) * DDIM + d0;

    float A0 = 1.0f, B0 = 0.0f, A1 = 1.0f, B1 = 0.0f;
#pragma unroll 8
    for (int t = 0; t < CHUNK; t++) {
        unsigned sp = *(const unsigned*)(S + base);
        unsigned xp = *(const unsigned*)(XB + base);
        float a0 = __expf(bf_lo(sp));
        float a1 = __expf(bf_hi(sp));
        B0 = fmaf(a0, B0, bf_lo(xp)); A0 *= a0;
        B1 = fmaf(a1, B1, bf_hi(xp)); A1 *= a1;
        base += DDIM;
    }
    const int chain = bq * DDIM + d0;
    float2 av; av.x = A0; av.y = A1;
    float2 bv; bv.x = B0; bv.y = B1;
    *(float2*)(AggA + (size_t)c * CHAINS + chain) = av;
    *(float2*)(AggB + (size_t)c * CHAINS + chain) = bv;
}

// ---------- K4: pass2 — serial scan over NC chunk aggregates per chain ----------
__global__ __launch_bounds__(256)
void scan_pass2(const float* __restrict__ AggA, const float* __restrict__ AggB,
                float* __restrict__ H0) {
    const int chain = blockIdx.x * 256 + threadIdx.x;   // 4096 chains
    float p = 0.0f;
#pragma unroll 8
    for (int c = 0; c < NC; c++) {
        H0[(size_t)c * CHAINS + chain] = p;
        p = AggA[(size_t)c * CHAINS + chain] * p + AggB[(size_t)c * CHAINS + chain];
    }
}

// ---------- K5: pass3 — apply chunk prefix, write h ----------
__global__ __launch_bounds__(256)
void scan_pass3(const u16* __restrict__ S, const u16* __restrict__ XB,
                const float* __restrict__ H0, float* __restrict__ out) {
    const int c = blockIdx.x, dblk = blockIdx.y, bq = blockIdx.z;
    const int d0 = dblk * 512 + threadIdx.x * 2;
    size_t base = ((size_t)(bq * T_SEQ + c * CHUNK)) * DDIM + d0;
    const int chain = bq * DDIM + d0;

    float2 h = *(const float2*)(H0 + (size_t)c * CHAINS + chain);
#pragma unroll 8
    for (int t = 0; t < CHUNK; t++) {
        unsigned sp = *(const unsigned*)(S + base);
        unsigned xp = *(const unsigned*)(XB + base);
        float a0 = __expf(bf_lo(sp));
        float a1 = __expf(bf_hi(sp));
        h.x = fmaf(a0, h.x, bf_lo(xp));
        h.y = fmaf(a1, h.y, bf_hi(xp));
        *(float2*)(out + base) = h;
        base += DDIM;
    }
}

// ---------- launch ----------
extern "C" void kernel_launch(void* const* d_in, const int* in_sizes, int n_in,
                              void* d_out, int out_size, void* d_ws, size_t ws_size,
                              hipStream_t stream) {
    const float* x   = (const float*)d_in[0];
    const float* Win = (const float*)d_in[1];
    const float* bin = (const float*)d_in[2];
    const float* Wg  = (const float*)d_in[3];
    const float* bg  = (const float*)d_in[4];
    const float* lam = (const float*)d_in[5];
    float* out = (float*)d_out;

    // ws layout (MiB): Wi_bf 0..2, Wg_bf 2..4, S 4..68, XB 68..132,
    // AggA 132..134, AggB 134..136, H0 136..138  (= 138 MiB)
    char* w = (char*)d_ws;
    u16* Wi_bf  = (u16*)(w);
    u16* Wg_bf  = (u16*)(w + (size_t)(2) * 1024 * 1024);
    u16* Sg     = (u16*)(w + (size_t)(4) * 1024 * 1024);
    u16* XBg    = (u16*)(w + (size_t)(68) * 1024 * 1024);
    float* AggA = (float*)(w + (size_t)(132) * 1024 * 1024);
    float* AggB = (float*)(w + (size_t)(134) * 1024 * 1024);
    float* H0   = (float*)(w + (size_t)(136) * 1024 * 1024);

    // x_bf16 staged in first 64 MiB of d_out (read by GEMM main loop AND
    // epilogue; dead after GEMM; pass3 then overwrites d_out with h)
    u16* Xbf = (u16*)d_out;

    // K1: one fused convert (x + both W)
    cvt_all<<<dim3((N4X + 2 * N4W) / 256), dim3(256), 0, stream>>>(
        x, Win, Wg, Xbf, Wi_bf, Wg_bf);

    // K2: fused gate GEMM + gating epilogue, register-pipelined schedule
    gemm_fused<<<dim3((DDIM / 128) * (MM / 256)), dim3(512), 0, stream>>>(
        Xbf, Wi_bf, Wg_bf, bin, bg, lam, Sg, XBg);

    // K3-K5: chunked scan over compact bf16 (S, XB)
    scan_pass1<<<dim3(NC, 2, BB), dim3(256), 0, stream>>>(Sg, XBg, AggA, AggB);
    scan_pass2<<<dim3(CHAINS / 256), dim3(256), 0, stream>>>(AggA, AggB, H0);
    scan_pass3<<<dim3(NC, 2, BB), dim3(256), 0, stream>>>(Sg, XBg, H0, out);
}